// Round 1
// baseline (604.318 us; speedup 1.0000x reference)
//
#include <hip/hip_runtime.h>

// Problem sizes: bs=2, T=8, H=W=128, dec=64, enc=32, nH=4, hh=ww=16
// x1 (2,64,8,64,64)  x2 (2,32,8,128,128)  attn (4,2,16,16,8,8)
// out (2,32,8,128,128) fp32

#define EPSV 1e-5f

// ws layout (float offsets)
#define U_OFF   0          // 2*64*8*128*128 = 16777216
#define HM_OFF  16777216   // 2*32*8*128*128 = 8388608
#define C1_OFF  25165824   // 8388608
#define WR1_OFF 33554432   // 96*9*32 = 27648
#define WR2_OFF 33582080   // 32*9*32 = 9216
#define ST_OFF  33591296   // 3 * 64
#define SC_OFF  33591488   // 6 * 32

// ---------------- upsample: U[b,o,t,2h+k,2w+l] = sum_c x1[b,c,t,h,w]*Wup[c,o,0,k,l] + bup[o]
__global__ __launch_bounds__(256) void k_up(const float* __restrict__ x1,
        const float* __restrict__ Wup, const float* __restrict__ bup,
        float* __restrict__ U) {
  int bid = blockIdx.x;
  int hw = (bid & 15) * 256 + threadIdx.x;   // 4096 positions per (b,o,t)
  int t = (bid >> 4) & 7;
  int o = (bid >> 7) & 63;
  int b = bid >> 13;
  int h = hw >> 6, w = hw & 63;
  const float4* W4 = (const float4*)Wup;     // [c*64+o] -> (k0l0,k0l1,k1l0,k1l1)
  const float* xp = x1 + (b*64*8 + t)*4096 + hw;
  float a00=0.f, a01=0.f, a10=0.f, a11=0.f;
  #pragma unroll 8
  for (int c=0;c<64;++c) {
    float xv = xp[c*32768];
    float4 wv = W4[c*64+o];
    a00 = fmaf(xv, wv.x, a00);
    a01 = fmaf(xv, wv.y, a01);
    a10 = fmaf(xv, wv.z, a10);
    a11 = fmaf(xv, wv.w, a11);
  }
  float bb = bup[o];
  float* up = U + ((b*64+o)*8+t)*16384 + h*256 + w*2;
  ((float2*)up)[0]       = make_float2(a00+bb, a01+bb);
  ((float2*)(up+128))[0] = make_float2(a10+bb, a11+bb);
}

// ---------------- attention (bilinear-resized A) fused with 128->32 MLP -> HM raw
__global__ __launch_bounds__(256) void k_ctxmlp(const float* __restrict__ x2,
        const float* __restrict__ attn, const float* __restrict__ Wmlp,
        const float* __restrict__ bmlp, float* __restrict__ HM) {
  int t = blockIdx.y, b = blockIdx.z;
  int pos = blockIdx.x*256 + threadIdx.x;    // x*128+y
  __shared__ float la[8192];                 // [n][ix][iy][s], 4*16*16*8
  float4* la4 = (float4*)la;
  const float4* g4 = (const float4*)attn;
  #pragma unroll
  for (int k=0;k<8;++k) {
    int i = k*256 + (int)threadIdx.x;        // float4 index: (n,ix,iy,s4)
    int s4 = i & 1, iy = (i>>1)&15, ix = (i>>5)&15, n = i>>9;
    la4[i] = g4[((((n*2+b)*16+ix)*16+iy)*8+t)*2 + s4];
  }
  __syncthreads();
  int x = pos >> 7, y = pos & 127;
  float ux = (x+0.5f)*0.125f - 0.5f;
  float uy = (y+0.5f)*0.125f - 0.5f;
  int ix0 = (int)floorf(ux), iy0 = (int)floorf(uy);
  float fx = ux - (float)ix0, fy = uy - (float)iy0;
  int ixa = max(ix0,0), ixb = min(ix0+1,15);
  int iya = max(iy0,0), iyb = min(iy0+1,15);
  float w00=(1.f-fx)*(1.f-fy), w01=(1.f-fx)*fy, w10=fx*(1.f-fy), w11=fx*fy;
  float a[4][8];
  #pragma unroll
  for (int n=0;n<4;++n) {
    const float4* p00 = la4 + ((n*16+ixa)*16+iya)*2;
    const float4* p01 = la4 + ((n*16+ixa)*16+iyb)*2;
    const float4* p10 = la4 + ((n*16+ixb)*16+iya)*2;
    const float4* p11 = la4 + ((n*16+ixb)*16+iyb)*2;
    #pragma unroll
    for (int q=0;q<2;++q) {
      float4 c00=p00[q], c01=p01[q], c10=p10[q], c11=p11[q];
      a[n][q*4+0] = w00*c00.x + w01*c01.x + w10*c10.x + w11*c11.x;
      a[n][q*4+1] = w00*c00.y + w01*c01.y + w10*c10.y + w11*c11.y;
      a[n][q*4+2] = w00*c00.z + w01*c01.z + w10*c10.z + w11*c11.z;
      a[n][q*4+3] = w00*c00.w + w01*c01.w + w10*c10.w + w11*c11.w;
    }
  }
  float acc[32];
  #pragma unroll
  for (int o=0;o<32;++o) acc[o] = bmlp[o];
  const float* x2p = x2 + b*4194304 + pos;
  #pragma unroll 4
  for (int c=0;c<32;++c) {
    float xr[8];
    #pragma unroll
    for (int s=0;s<8;++s) xr[s] = x2p[(c*8+s)*16384];
    #pragma unroll
    for (int n=0;n<4;++n) {
      float ctx = 0.f;
      #pragma unroll
      for (int s=0;s<8;++s) ctx = fmaf(a[n][s], xr[s], ctx);
      const float* wrow = Wmlp + (c*4+n)*32;
      #pragma unroll
      for (int o=0;o<32;++o) acc[o] = fmaf(ctx, wrow[o], acc[o]);
    }
  }
  float* hp = HM + (b*256 + t)*16384 + pos;
  #pragma unroll
  for (int o=0;o<32;++o) hp[o*131072] = acc[o];
}

// ---------------- per-channel sum/sumsq over [b][32][131072] layout
__global__ __launch_bounds__(256) void k_stats(const float* __restrict__ src, float* __restrict__ st) {
  int bid = blockIdx.x;                      // b*1024 + ch*32 + span
  int span = bid & 31, ch = (bid>>5)&31, b = bid>>10;
  const float4* p4 = (const float4*)(src + (b*32+ch)*131072 + span*4096);
  float s=0.f, q=0.f;
  #pragma unroll
  for (int k=0;k<4;++k) {
    float4 v = p4[k*256 + threadIdx.x];
    s += v.x+v.y+v.z+v.w;
    q += v.x*v.x + v.y*v.y + v.z*v.z + v.w*v.w;
  }
  #pragma unroll
  for (int off=32; off>0; off>>=1) { s += __shfl_down(s,off); q += __shfl_down(q,off); }
  __shared__ float ls[4], lq[4];
  int lane = threadIdx.x & 63, wv = threadIdx.x >> 6;
  if (lane==0) { ls[wv]=s; lq[wv]=q; }
  __syncthreads();
  if (threadIdx.x==0) {
    atomicAdd(&st[ch],    ls[0]+ls[1]+ls[2]+ls[3]);
    atomicAdd(&st[32+ch], lq[0]+lq[1]+lq[2]+lq[3]);
  }
}

__global__ void k_finalize(const float* __restrict__ st, const float* __restrict__ g,
                           const float* __restrict__ be, float* __restrict__ sc, float* __restrict__ sh) {
  int c = threadIdx.x;
  if (c < 32) {
    float mean = st[c] * (1.f/262144.f);
    float var  = st[32+c] * (1.f/262144.f) - mean*mean;
    float s = g[c] / sqrtf(var + EPSV);
    sc[c] = s;
    sh[c] = be[c] - mean*s;
  }
}

// ---------------- repack conv weights: wr[(cin*9+tap)*32 + o] = Wc[o][cin][tap]
__global__ __launch_bounds__(256) void k_repack(const float* __restrict__ Wc1, const float* __restrict__ Wc2,
        float* __restrict__ wr1, float* __restrict__ wr2) {
  int i = blockIdx.x*256 + threadIdx.x;
  if (i < 27648) { int o = i & 31, r = i >> 5; wr1[i] = Wc1[o*864 + r]; }
  if (i < 9216)  { int o = i & 31, r = i >> 5; wr2[i] = Wc2[o*288 + r]; }
}

// ---------------- 3x3 conv, depth-1, same-pad; 16x16 tile, 8-ch LDS chunks.
// FIRST: input = [bn_relu(HM) (32ch) ; U (64ch)]; else input = bn_relu(C1) (32ch)
template<int CIN, bool FIRST>
__global__ __launch_bounds__(256) void k_conv(
    const float* __restrict__ srcA, const float* __restrict__ srcB,
    const float* __restrict__ wr, const float* __restrict__ bias,
    const float* __restrict__ sc, const float* __restrict__ sh,
    float* __restrict__ dst) {
  int t = blockIdx.y, b = blockIdx.z;
  int x0 = (int)(blockIdx.x >> 3) * 16, y0 = (int)(blockIdx.x & 7) * 16;
  __shared__ float tile[8*18*18];            // 2592 floats
  float acc[32];
  #pragma unroll
  for (int o=0;o<32;++o) acc[o] = bias[o];
  const int NCHUNK = CIN/8;
  for (int cc=0; cc<NCHUNK; ++cc) {
    __syncthreads();
    for (int i=threadIdx.x; i<2592; i+=256) {
      int ci = i / 324;
      int rem = i - ci*324;
      int r = rem / 18;
      int col = rem - r*18;
      int X = x0 - 1 + r, Y = y0 - 1 + col;
      float v = 0.f;
      if ((unsigned)X < 128u && (unsigned)Y < 128u) {
        int cg = cc*8+ci;
        if (FIRST) {
          if (cg < 32) {
            v = srcA[((b*32+cg)*8+t)*16384 + X*128+Y];
            v = fmaxf(fmaf(v, sc[cg], sh[cg]), 0.f);
          } else {
            v = srcB[((b*64+(cg-32))*8+t)*16384 + X*128+Y];
          }
        } else {
          v = srcA[((b*32+cg)*8+t)*16384 + X*128+Y];
          v = fmaxf(fmaf(v, sc[cg], sh[cg]), 0.f);
        }
      }
      tile[i] = v;
    }
    __syncthreads();
    int tx = threadIdx.x & 15, ty = threadIdx.x >> 4;
    #pragma unroll
    for (int ci=0; ci<8; ++ci) {
      const float* trow = &tile[ci*324 + ty*18 + tx];
      const float* wp0 = wr + (cc*8+ci)*9*32;
      #pragma unroll
      for (int dy=0; dy<3; ++dy) {
        #pragma unroll
        for (int dx=0; dx<3; ++dx) {
          float xv = trow[dy*18+dx];
          const float* wp = wp0 + (dy*3+dx)*32;
          #pragma unroll
          for (int o=0;o<32;++o) acc[o] = fmaf(xv, wp[o], acc[o]);
        }
      }
    }
  }
  int x = x0 + (threadIdx.x>>4), y = y0 + (threadIdx.x&15);
  float* dp = dst + (b*256+t)*16384 + x*128 + y;
  #pragma unroll
  for (int o=0;o<32;++o) dp[o*131072] = acc[o];
}

// ---------------- final BN+ReLU in place on d_out
__global__ __launch_bounds__(256) void k_bnrelu(float* __restrict__ out,
        const float* __restrict__ sc, const float* __restrict__ sh) {
  int i = blockIdx.x*256 + threadIdx.x;      // float4 index, total 2097152
  int ch = (i >> 15) & 31;
  float s = sc[ch], h = sh[ch];
  float4* p = (float4*)out;
  float4 v = p[i];
  v.x = fmaxf(fmaf(v.x,s,h),0.f);
  v.y = fmaxf(fmaf(v.y,s,h),0.f);
  v.z = fmaxf(fmaf(v.z,s,h),0.f);
  v.w = fmaxf(fmaf(v.w,s,h),0.f);
  p[i] = v;
}

extern "C" void kernel_launch(void* const* d_in, const int* in_sizes, int n_in,
                              void* d_out, int out_size, void* d_ws, size_t ws_size,
                              hipStream_t stream) {
  (void)in_sizes; (void)n_in; (void)out_size; (void)ws_size;
  const float* x1   = (const float*)d_in[0];
  const float* x2   = (const float*)d_in[1];
  const float* attn = (const float*)d_in[2];
  const float* Wup  = (const float*)d_in[3];
  const float* bup  = (const float*)d_in[4];
  const float* Wmlp = (const float*)d_in[5];
  const float* bmlp = (const float*)d_in[6];
  const float* gmlp = (const float*)d_in[7];
  const float* bemlp= (const float*)d_in[8];
  const float* Wc1  = (const float*)d_in[9];
  const float* bc1  = (const float*)d_in[10];
  const float* gc1  = (const float*)d_in[11];
  const float* bec1 = (const float*)d_in[12];
  const float* Wc2  = (const float*)d_in[13];
  const float* bc2  = (const float*)d_in[14];
  const float* gc2  = (const float*)d_in[15];
  const float* bec2 = (const float*)d_in[16];
  float* ws  = (float*)d_ws;
  float* out = (float*)d_out;

  float* U   = ws + U_OFF;
  float* HM  = ws + HM_OFF;
  float* C1  = ws + C1_OFF;
  float* wr1 = ws + WR1_OFF;
  float* wr2 = ws + WR2_OFF;
  float* st1 = ws + ST_OFF;
  float* st2 = st1 + 64;
  float* st3 = st2 + 64;
  float* sc1 = ws + SC_OFF;  float* sh1 = sc1+32;
  float* sc2 = sh1+32;       float* sh2 = sc2+32;
  float* sc3 = sh2+32;       float* sh3 = sc3+32;

  hipMemsetAsync(st1, 0, 192*sizeof(float), stream);
  k_up<<<16384, 256, 0, stream>>>(x1, Wup, bup, U);
  k_repack<<<108, 256, 0, stream>>>(Wc1, Wc2, wr1, wr2);
  k_ctxmlp<<<dim3(64,8,2), 256, 0, stream>>>(x2, attn, Wmlp, bmlp, HM);
  k_stats<<<2048, 256, 0, stream>>>(HM, st1);
  k_finalize<<<1, 32, 0, stream>>>(st1, gmlp, bemlp, sc1, sh1);
  k_conv<96,true><<<dim3(64,8,2), 256, 0, stream>>>(HM, U, wr1, bc1, sc1, sh1, C1);
  k_stats<<<2048, 256, 0, stream>>>(C1, st2);
  k_finalize<<<1, 32, 0, stream>>>(st2, gc1, bec1, sc2, sh2);
  k_conv<32,false><<<dim3(64,8,2), 256, 0, stream>>>(C1, nullptr, wr2, bc2, sc2, sh2, out);
  k_stats<<<2048, 256, 0, stream>>>(out, st3);
  k_finalize<<<1, 32, 0, stream>>>(st3, gc2, bec2, sc3, sh3);
  k_bnrelu<<<8192, 256, 0, stream>>>(out, sc3, sh3);
}

// Round 2
// 366.094 us; speedup vs baseline: 1.6507x; 1.6507x over previous
//
#include <hip/hip_runtime.h>

// Problem sizes: bs=2, T=8, H=W=128, dec=64, enc=32, nH=4, hh=ww=16
// x1 (2,64,8,64,64)  x2 (2,32,8,128,128)  attn (4,2,16,16,8,8)
// out (2,32,8,128,128) fp32

#define EPSV 1e-5f

typedef __attribute__((ext_vector_type(8))) short short8;
typedef __attribute__((ext_vector_type(4))) float floatx4;

__device__ inline short f2bf(float f) {
  union { float f; unsigned u; } v; v.f = f;
  unsigned r = (v.u + 0x7fffu + ((v.u >> 16) & 1u)) >> 16;
  return (short)r;
}
__device__ inline float bf2f(short s) {
  union { unsigned u; float f; } v; v.u = ((unsigned)(unsigned short)s) << 16;
  return v.f;
}

// ws layout (float offsets)
#define U_OFF    0           // 2*64*8*128*128 = 16777216 floats (fp32 planar)
#define HMB_OFF  16777216    // 8388608 bf16 = 4194304 floats (channel-last)
#define C1B_OFF  20971520    // 8388608 bf16 = 4194304 floats (channel-last)
#define WB1_OFF  25165824    // 27648 bf16 = 13824 floats
#define WB2_OFF  25179648    // 9216 bf16  = 4608 floats
#define ST_OFF   25184256    // 3 * 64 floats
#define SC_OFF   25184448    // 6 * 32 floats

// ---------------- upsample: U[b,o,t,2h+k,2w+l] = sum_c x1[b,c,t,h,w]*Wup[c,o,0,k,l] + bup[o]
__global__ __launch_bounds__(256) void k_up(const float* __restrict__ x1,
        const float* __restrict__ Wup, const float* __restrict__ bup,
        float* __restrict__ U) {
  int bid = blockIdx.x;
  int hw = (bid & 15) * 256 + threadIdx.x;   // 4096 positions per (b,o,t)
  int t = (bid >> 4) & 7;
  int o = (bid >> 7) & 63;
  int b = bid >> 13;
  int h = hw >> 6, w = hw & 63;
  const float4* W4 = (const float4*)Wup;     // [c*64+o] -> (k0l0,k0l1,k1l0,k1l1)
  const float* xp = x1 + (b*64*8 + t)*4096 + hw;
  float a00=0.f, a01=0.f, a10=0.f, a11=0.f;
  #pragma unroll 8
  for (int c=0;c<64;++c) {
    float xv = xp[c*32768];
    float4 wv = W4[c*64+o];
    a00 = fmaf(xv, wv.x, a00);
    a01 = fmaf(xv, wv.y, a01);
    a10 = fmaf(xv, wv.z, a10);
    a11 = fmaf(xv, wv.w, a11);
  }
  float bb = bup[o];
  float* up = U + ((b*64+o)*8+t)*16384 + h*256 + w*2;
  ((float2*)up)[0]       = make_float2(a00+bb, a01+bb);
  ((float2*)(up+128))[0] = make_float2(a10+bb, a11+bb);
}

// ---------------- attention (bilinear-resized A) fused with 128->32 MLP -> HM (bf16 channel-last)
__global__ __launch_bounds__(256) void k_ctxmlp(const float* __restrict__ x2,
        const float* __restrict__ attn, const float* __restrict__ Wmlp,
        const float* __restrict__ bmlp, short* __restrict__ HMb) {
  int t = blockIdx.y, b = blockIdx.z;
  int pos = blockIdx.x*256 + threadIdx.x;    // x*128+y
  __shared__ float la[8192];                 // [n][ix][iy][s], 4*16*16*8
  float4* la4 = (float4*)la;
  const float4* g4 = (const float4*)attn;
  #pragma unroll
  for (int k=0;k<8;++k) {
    int i = k*256 + (int)threadIdx.x;        // float4 index: (n,ix,iy,s4)
    int s4 = i & 1, iy = (i>>1)&15, ix = (i>>5)&15, n = i>>9;
    la4[i] = g4[((((n*2+b)*16+ix)*16+iy)*8+t)*2 + s4];
  }
  __syncthreads();
  int x = pos >> 7, y = pos & 127;
  float ux = (x+0.5f)*0.125f - 0.5f;
  float uy = (y+0.5f)*0.125f - 0.5f;
  int ix0 = (int)floorf(ux), iy0 = (int)floorf(uy);
  float fx = ux - (float)ix0, fy = uy - (float)iy0;
  int ixa = max(ix0,0), ixb = min(ix0+1,15);
  int iya = max(iy0,0), iyb = min(iy0+1,15);
  float w00=(1.f-fx)*(1.f-fy), w01=(1.f-fx)*fy, w10=fx*(1.f-fy), w11=fx*fy;
  float a[4][8];
  #pragma unroll
  for (int n=0;n<4;++n) {
    const float4* p00 = la4 + ((n*16+ixa)*16+iya)*2;
    const float4* p01 = la4 + ((n*16+ixa)*16+iyb)*2;
    const float4* p10 = la4 + ((n*16+ixb)*16+iya)*2;
    const float4* p11 = la4 + ((n*16+ixb)*16+iyb)*2;
    #pragma unroll
    for (int q=0;q<2;++q) {
      float4 c00=p00[q], c01=p01[q], c10=p10[q], c11=p11[q];
      a[n][q*4+0] = w00*c00.x + w01*c01.x + w10*c10.x + w11*c11.x;
      a[n][q*4+1] = w00*c00.y + w01*c01.y + w10*c10.y + w11*c11.y;
      a[n][q*4+2] = w00*c00.z + w01*c01.z + w10*c10.z + w11*c11.z;
      a[n][q*4+3] = w00*c00.w + w01*c01.w + w10*c10.w + w11*c11.w;
    }
  }
  float acc[32];
  #pragma unroll
  for (int o=0;o<32;++o) acc[o] = bmlp[o];
  const float* x2p = x2 + b*4194304 + pos;
  #pragma unroll 4
  for (int c=0;c<32;++c) {
    float xr[8];
    #pragma unroll
    for (int s=0;s<8;++s) xr[s] = x2p[(c*8+s)*16384];
    #pragma unroll
    for (int n=0;n<4;++n) {
      float ctx = 0.f;
      #pragma unroll
      for (int s=0;s<8;++s) ctx = fmaf(a[n][s], xr[s], ctx);
      const float* wrow = Wmlp + (c*4+n)*32;
      #pragma unroll
      for (int o=0;o<32;++o) acc[o] = fmaf(ctx, wrow[o], acc[o]);
    }
  }
  short8* hp = (short8*)(HMb + ((long)((b*8+t)*16384 + pos)) * 32);
  #pragma unroll
  for (int g=0; g<4; ++g) {
    short8 v;
    #pragma unroll
    for (int j=0;j<8;++j) v[j] = f2bf(acc[g*8+j]);
    hp[g] = v;
  }
}

// ---------------- stats over channel-last bf16 [262144 pos][32 ch]
__global__ __launch_bounds__(256) void k_stats_cl(const unsigned* __restrict__ src, float* __restrict__ st) {
  __shared__ float sb[64];
  if (threadIdx.x < 64) sb[threadIdx.x] = 0.f;
  __syncthreads();
  int cp = threadIdx.x & 15;          // channel pair index
  int pg = threadIdx.x >> 4;          // 0..15
  long pbase = (long)blockIdx.x * 256;
  float s0=0.f,q0=0.f,s1=0.f,q1=0.f;
  #pragma unroll 4
  for (int it = 0; it < 16; ++it) {
    long pos = pbase + it*16 + pg;
    unsigned d = src[pos*16 + cp];
    float v0 = bf2f((short)(d & 0xffffu));
    float v1 = bf2f((short)(d >> 16));
    s0+=v0; q0+=v0*v0; s1+=v1; q1+=v1*v1;
  }
  s0 += __shfl_xor(s0,16); s0 += __shfl_xor(s0,32);
  q0 += __shfl_xor(q0,16); q0 += __shfl_xor(q0,32);
  s1 += __shfl_xor(s1,16); s1 += __shfl_xor(s1,32);
  q1 += __shfl_xor(q1,16); q1 += __shfl_xor(q1,32);
  if ((threadIdx.x & 63) < 16) {
    atomicAdd(&sb[2*cp],    s0); atomicAdd(&sb[2*cp+1],    s1);
    atomicAdd(&sb[32+2*cp], q0); atomicAdd(&sb[32+2*cp+1], q1);
  }
  __syncthreads();
  if (threadIdx.x < 64) atomicAdd(&st[threadIdx.x], sb[threadIdx.x]);
}

// ---------------- per-channel sum/sumsq over fp32 planar [b][32][131072]
__global__ __launch_bounds__(256) void k_stats(const float* __restrict__ src, float* __restrict__ st) {
  int bid = blockIdx.x;                      // b*1024 + ch*32 + span
  int span = bid & 31, ch = (bid>>5)&31, b = bid>>10;
  const float4* p4 = (const float4*)(src + (b*32+ch)*131072 + span*4096);
  float s=0.f, q=0.f;
  #pragma unroll
  for (int k=0;k<4;++k) {
    float4 v = p4[k*256 + threadIdx.x];
    s += v.x+v.y+v.z+v.w;
    q += v.x*v.x + v.y*v.y + v.z*v.z + v.w*v.w;
  }
  #pragma unroll
  for (int off=32; off>0; off>>=1) { s += __shfl_down(s,off); q += __shfl_down(q,off); }
  __shared__ float ls[4], lq[4];
  int lane = threadIdx.x & 63, wv = threadIdx.x >> 6;
  if (lane==0) { ls[wv]=s; lq[wv]=q; }
  __syncthreads();
  if (threadIdx.x==0) {
    atomicAdd(&st[ch],    ls[0]+ls[1]+ls[2]+ls[3]);
    atomicAdd(&st[32+ch], lq[0]+lq[1]+lq[2]+lq[3]);
  }
}

__global__ void k_finalize(const float* __restrict__ st, const float* __restrict__ g,
                           const float* __restrict__ be, float* __restrict__ sc, float* __restrict__ sh) {
  int c = threadIdx.x;
  if (c < 32) {
    float mean = st[c] * (1.f/262144.f);
    float var  = st[32+c] * (1.f/262144.f) - mean*mean;
    float s = g[c] / sqrtf(var + EPSV);
    sc[c] = s;
    sh[c] = be[c] - mean*s;
  }
}

// ---------------- prepack conv weights into MFMA B-fragment order (bf16)
// wb[cc][tap][nt][lane][j] = W[o = nt*16+(lane&15)][cin = cc*32+(lane>>4)*8+j][tap]
__global__ __launch_bounds__(256) void k_repackb(const float* __restrict__ Wc1, const float* __restrict__ Wc2,
        short* __restrict__ wb1, short* __restrict__ wb2) {
  int i = blockIdx.x*256 + threadIdx.x;
  if (i < 27648) {
    int cc = i / 9216, r = i % 9216;
    int tap = r / 1024, r2 = r % 1024;
    int nt = r2 >> 9, lane = (r2 >> 3) & 63, j = r2 & 7;
    int o = nt*16 + (lane & 15);
    int cin = cc*32 + (lane >> 4)*8 + j;
    wb1[i] = f2bf(Wc1[(o*96 + cin)*9 + tap]);
  }
  if (i < 9216) {
    int tap = i / 1024, r2 = i % 1024;
    int nt = r2 >> 9, lane = (r2 >> 3) & 63, j = r2 & 7;
    int o = nt*16 + (lane & 15);
    int cin = (lane >> 4)*8 + j;
    wb2[i] = f2bf(Wc2[(o*32 + cin)*9 + tap]);
  }
}

// ---------------- 3x3 conv via bf16 MFMA implicit GEMM.
// FIRST (conv1): chunk0 = bn_relu(HMb) (bf16 CL), chunks1-2 = U (fp32 planar raw); out = C1b bf16 CL.
// !FIRST (conv2): chunk0 = bn_relu(C1b); out = fp32 planar (d_out).
template<int NCHUNK, bool FIRST>
__global__ __launch_bounds__(256) void k_conv_mfma(
    const short* __restrict__ srcCL, const float* __restrict__ srcU,
    const short* __restrict__ wb, const float* __restrict__ bias,
    const float* __restrict__ sc, const float* __restrict__ sh,
    short* __restrict__ dstCL, float* __restrict__ dstP) {
  constexpr int SMEM = FIRST ? 25920 : 33792;   // stage 324*40*2B vs fp32 transpose 256*33*4B
  __shared__ __align__(16) char smem[SMEM];
  short* stage = (short*)smem;

  int t = blockIdx.y, b = blockIdx.z;
  int x0 = (int)(blockIdx.x >> 3) * 16, y0 = (int)(blockIdx.x & 7) * 16;
  int tid = threadIdx.x, lane = tid & 63, w = tid >> 6;

  float bias0 = bias[lane & 15], bias1 = bias[16 + (lane & 15)];
  floatx4 acc[4][2];
  #pragma unroll
  for (int mt=0; mt<4; ++mt) {
    acc[mt][0] = (floatx4){bias0,bias0,bias0,bias0};
    acc[mt][1] = (floatx4){bias1,bias1,bias1,bias1};
  }

  for (int cc=0; cc<NCHUNK; ++cc) {
    __syncthreads();
    if (cc == 0) {
      // bf16 channel-last source with BN+ReLU
      #pragma unroll
      for (int g=0; g<4; ++g) {
        float s0=sc[g*8+0],s1=sc[g*8+1],s2=sc[g*8+2],s3=sc[g*8+3];
        float s4=sc[g*8+4],s5=sc[g*8+5],s6=sc[g*8+6],s7=sc[g*8+7];
        float h0=sh[g*8+0],h1=sh[g*8+1],h2=sh[g*8+2],h3=sh[g*8+3];
        float h4=sh[g*8+4],h5=sh[g*8+5],h6=sh[g*8+6],h7=sh[g*8+7];
        for (int p=tid; p<324; p+=256) {
          int r = p/18, c = p - r*18;
          int X = x0 - 1 + r, Y = y0 - 1 + c;
          short8 val = (short8)0;
          if ((unsigned)X < 128u && (unsigned)Y < 128u) {
            short8 raw = *(const short8*)(srcCL + (((long)(b*8+t)*16384 + X*128 + Y) * 32 + g*8));
            val[0]=f2bf(fmaxf(fmaf(bf2f(raw[0]),s0,h0),0.f));
            val[1]=f2bf(fmaxf(fmaf(bf2f(raw[1]),s1,h1),0.f));
            val[2]=f2bf(fmaxf(fmaf(bf2f(raw[2]),s2,h2),0.f));
            val[3]=f2bf(fmaxf(fmaf(bf2f(raw[3]),s3,h3),0.f));
            val[4]=f2bf(fmaxf(fmaf(bf2f(raw[4]),s4,h4),0.f));
            val[5]=f2bf(fmaxf(fmaf(bf2f(raw[5]),s5,h5),0.f));
            val[6]=f2bf(fmaxf(fmaf(bf2f(raw[6]),s6,h6),0.f));
            val[7]=f2bf(fmaxf(fmaf(bf2f(raw[7]),s7,h7),0.f));
          }
          *(short8*)(stage + p*40 + g*8) = val;
        }
      }
    } else {
      int cbase = (cc-1)*32;
      #pragma unroll
      for (int g=0; g<4; ++g) {
        for (int p=tid; p<324; p+=256) {
          int r = p/18, c = p - r*18;
          int X = x0 - 1 + r, Y = y0 - 1 + c;
          short8 val = (short8)0;
          if ((unsigned)X < 128u && (unsigned)Y < 128u) {
            const float* up = srcU + ((long)(b*64 + cbase + g*8)*8 + t)*16384 + X*128 + Y;
            #pragma unroll
            for (int j=0;j<8;++j) val[j] = f2bf(up[(long)j*131072]);
          }
          *(short8*)(stage + p*40 + g*8) = val;
        }
      }
    }
    __syncthreads();
    const short8* wbp = (const short8*)wb + (long)cc*9*2*64;
    #pragma unroll
    for (int tap=0; tap<9; ++tap) {
      int dy = tap/3, dx = tap - dy*3;
      short8 b0 = wbp[(tap*2+0)*64 + lane];
      short8 b1 = wbp[(tap*2+1)*64 + lane];
      #pragma unroll
      for (int mt=0; mt<4; ++mt) {
        int p = (w*4 + mt + dy)*18 + (lane & 15) + dx;
        short8 a = *(const short8*)(stage + p*40 + (lane>>4)*8);
        acc[mt][0] = __builtin_amdgcn_mfma_f32_16x16x32_bf16(a, b0, acc[mt][0], 0,0,0);
        acc[mt][1] = __builtin_amdgcn_mfma_f32_16x16x32_bf16(a, b1, acc[mt][1], 0,0,0);
      }
    }
  }

  __syncthreads();
  if (FIRST) {
    // transpose to [pos][ch] bf16, then coalesced channel-last stores
    short* tr = (short*)smem;
    #pragma unroll
    for (int mt=0; mt<4; ++mt) {
      int prow = w*4 + mt;
      #pragma unroll
      for (int nt=0; nt<2; ++nt) {
        #pragma unroll
        for (int r=0; r<4; ++r) {
          int m = (lane>>4)*4 + r;
          tr[(prow*16 + m)*32 + nt*16 + (lane&15)] = f2bf(acc[mt][nt][r]);
        }
      }
    }
    __syncthreads();
    int px = tid >> 4, py = tid & 15;
    short8* d8 = (short8*)(dstCL + (((long)(b*8+t)*128 + x0+px)*128 + (y0+py))*32);
    const short8* s8 = (const short8*)(tr + tid*32);
    d8[0]=s8[0]; d8[1]=s8[1]; d8[2]=s8[2]; d8[3]=s8[3];
  } else {
    // transpose to [pos][ch] fp32 (pad 33), then planar stores
    float* trf = (float*)smem;
    #pragma unroll
    for (int mt=0; mt<4; ++mt) {
      int prow = w*4 + mt;
      #pragma unroll
      for (int nt=0; nt<2; ++nt) {
        #pragma unroll
        for (int r=0; r<4; ++r) {
          int m = (lane>>4)*4 + r;
          trf[(prow*16 + m)*33 + nt*16 + (lane&15)] = acc[mt][nt][r];
        }
      }
    }
    __syncthreads();
    int px = tid >> 4, py = tid & 15;
    #pragma unroll
    for (int ch=0; ch<32; ++ch) {
      dstP[((long)(b*32+ch)*8 + t)*16384 + (x0+px)*128 + (y0+py)] = trf[tid*33 + ch];
    }
  }
}

// ---------------- final BN+ReLU in place on d_out
__global__ __launch_bounds__(256) void k_bnrelu(float* __restrict__ out,
        const float* __restrict__ sc, const float* __restrict__ sh) {
  int i = blockIdx.x*256 + threadIdx.x;      // float4 index, total 2097152
  int ch = (i >> 15) & 31;
  float s = sc[ch], h = sh[ch];
  float4* p = (float4*)out;
  float4 v = p[i];
  v.x = fmaxf(fmaf(v.x,s,h),0.f);
  v.y = fmaxf(fmaf(v.y,s,h),0.f);
  v.z = fmaxf(fmaf(v.z,s,h),0.f);
  v.w = fmaxf(fmaf(v.w,s,h),0.f);
  p[i] = v;
}

extern "C" void kernel_launch(void* const* d_in, const int* in_sizes, int n_in,
                              void* d_out, int out_size, void* d_ws, size_t ws_size,
                              hipStream_t stream) {
  (void)in_sizes; (void)n_in; (void)out_size; (void)ws_size;
  const float* x1   = (const float*)d_in[0];
  const float* x2   = (const float*)d_in[1];
  const float* attn = (const float*)d_in[2];
  const float* Wup  = (const float*)d_in[3];
  const float* bup  = (const float*)d_in[4];
  const float* Wmlp = (const float*)d_in[5];
  const float* bmlp = (const float*)d_in[6];
  const float* gmlp = (const float*)d_in[7];
  const float* bemlp= (const float*)d_in[8];
  const float* Wc1  = (const float*)d_in[9];
  const float* bc1  = (const float*)d_in[10];
  const float* gc1  = (const float*)d_in[11];
  const float* bec1 = (const float*)d_in[12];
  const float* Wc2  = (const float*)d_in[13];
  const float* bc2  = (const float*)d_in[14];
  const float* gc2  = (const float*)d_in[15];
  const float* bec2 = (const float*)d_in[16];
  float* ws  = (float*)d_ws;
  float* out = (float*)d_out;

  float* U    = ws + U_OFF;
  short* HMb  = (short*)(ws + HMB_OFF);
  short* C1b  = (short*)(ws + C1B_OFF);
  short* wb1  = (short*)(ws + WB1_OFF);
  short* wb2  = (short*)(ws + WB2_OFF);
  float* st1  = ws + ST_OFF;
  float* st2  = st1 + 64;
  float* st3  = st2 + 64;
  float* sc1  = ws + SC_OFF;  float* sh1 = sc1+32;
  float* sc2  = sh1+32;       float* sh2 = sc2+32;
  float* sc3  = sh2+32;       float* sh3 = sc3+32;

  hipMemsetAsync(st1, 0, 192*sizeof(float), stream);
  k_up<<<16384, 256, 0, stream>>>(x1, Wup, bup, U);
  k_repackb<<<108, 256, 0, stream>>>(Wc1, Wc2, wb1, wb2);
  k_ctxmlp<<<dim3(64,8,2), 256, 0, stream>>>(x2, attn, Wmlp, bmlp, HMb);
  k_stats_cl<<<1024, 256, 0, stream>>>((const unsigned*)HMb, st1);
  k_finalize<<<1, 32, 0, stream>>>(st1, gmlp, bemlp, sc1, sh1);
  k_conv_mfma<3,true><<<dim3(64,8,2), 256, 0, stream>>>(HMb, U, wb1, bc1, sc1, sh1, C1b, nullptr);
  k_stats_cl<<<1024, 256, 0, stream>>>((const unsigned*)C1b, st2);
  k_finalize<<<1, 32, 0, stream>>>(st2, gc1, bec1, sc2, sh2);
  k_conv_mfma<1,false><<<dim3(64,8,2), 256, 0, stream>>>(C1b, nullptr, wb2, bc2, sc2, sh2, nullptr, out);
  k_stats<<<2048, 256, 0, stream>>>(out, st3);
  k_finalize<<<1, 32, 0, stream>>>(st3, gc2, bec2, sc3, sh3);
  k_bnrelu<<<8192, 256, 0, stream>>>(out, sc3, sh3);
}

// Round 3
// 322.888 us; speedup vs baseline: 1.8716x; 1.1338x over previous
//
#include <hip/hip_runtime.h>

// Problem sizes: bs=2, T=8, H=W=128, dec=64, enc=32, nH=4, hh=ww=16
// x1 (2,64,8,64,64)  x2 (2,32,8,128,128)  attn (4,2,16,16,8,8)
// out (2,32,8,128,128) fp32

#define EPSV 1e-5f

typedef __attribute__((ext_vector_type(8))) short short8;
typedef __attribute__((ext_vector_type(4))) short short4v;
typedef __attribute__((ext_vector_type(4))) float floatx4;

__device__ inline short f2bf(float f) {
  union { float f; unsigned u; } v; v.f = f;
  unsigned r = (v.u + 0x7fffu + ((v.u >> 16) & 1u)) >> 16;
  return (short)r;
}
__device__ inline float bf2f(short s) {
  union { unsigned u; float f; } v; v.u = ((unsigned)(unsigned short)s) << 16;
  return v.f;
}

// ws layout (float offsets)
#define UB_OFF   0           // Ub bf16 CL: 2*8*16384 pos * 64 ch = 16.78M bf16 = 8388608 floats
#define HMB_OFF  8388608     // 4194304 floats (bf16 CL, 32 ch)
#define C1B_OFF  12582912    // 4194304
#define C2B_OFF  16777216    // 4194304
#define WB1_OFF  20971520    // 13824
#define WB2_OFF  20985344    // 4608
#define WUP_OFF  20989952    // 8192
#define ST_OFF   20998144    // 192
#define SC_OFF   20998336    // 192

// ---------------- prepack weights (conv B-fragments + upsample B-fragments)
__global__ __launch_bounds__(256) void k_repackb(const float* __restrict__ Wc1, const float* __restrict__ Wc2,
        const float* __restrict__ Wup,
        short* __restrict__ wb1, short* __restrict__ wb2, short* __restrict__ wupb) {
  int i = blockIdx.x*256 + threadIdx.x;
  if (i < 27648) {
    int cc = i / 9216, r = i % 9216;
    int tap = r / 1024, r2 = r % 1024;
    int nt = r2 >> 9, lane = (r2 >> 3) & 63, j = r2 & 7;
    int o = nt*16 + (lane & 15);
    int cin = cc*32 + (lane >> 4)*8 + j;
    wb1[i] = f2bf(Wc1[(o*96 + cin)*9 + tap]);
  }
  if (i < 9216) {
    int tap = i / 1024, r2 = i % 1024;
    int nt = r2 >> 9, lane = (r2 >> 3) & 63, j = r2 & 7;
    int o = nt*16 + (lane & 15);
    int cin = (lane >> 4)*8 + j;
    wb2[i] = f2bf(Wc2[(o*32 + cin)*9 + tap]);
  }
  if (i < 16384) {
    // i = ((p*2+kb)*4+nt)*512 + lane*8 + j
    int j = i & 7, lane = (i >> 3) & 63, r = i >> 9;
    int nt = r & 3, kb = (r >> 2) & 1, p = r >> 3;
    int c = kb*32 + (lane >> 4)*8 + j;
    int o = nt*16 + (lane & 15);
    wupb[i] = f2bf(Wup[(c*64 + o)*4 + p]);
  }
}

// ---------------- upsample via MFMA: per block one (b,t,parity,chunk of 256 input pos)
// Ub[((b*8+t)*16384 + X*128+Y)*64 + o] bf16
__global__ __launch_bounds__(256) void k_up_mfma(const float* __restrict__ x1,
        const short* __restrict__ wupb, const float* __restrict__ bup,
        short* __restrict__ Ub) {
  __shared__ __align__(16) char smem[34816];   // stageA 32KB | trb 256*68*2B
  short8* stage = (short8*)smem;
  int t = blockIdx.y, b = blockIdx.z;
  int chunk = blockIdx.x >> 2, parity = blockIdx.x & 3;
  int tid = threadIdx.x, lane = tid & 63, w = tid >> 6;

  {
    const float* xp = x1 + ((long)(b*64)*8 + t)*4096 + chunk*256 + tid;
    #pragma unroll
    for (int o8 = 0; o8 < 8; ++o8) {
      short8 v;
      #pragma unroll
      for (int j = 0; j < 8; ++j) v[j] = f2bf(xp[(long)(o8*8+j)*32768]);
      int kb = o8 >> 2, cq = o8 & 3;
      stage[(kb*16 + (tid>>4))*64 + cq*16 + (tid&15)] = v;
    }
  }
  __syncthreads();

  floatx4 acc[4][4];
  #pragma unroll
  for (int nt=0; nt<4; ++nt) {
    float bb = bup[nt*16 + (lane&15)];
    #pragma unroll
    for (int mt=0; mt<4; ++mt) acc[mt][nt] = (floatx4){bb,bb,bb,bb};
  }
  const short8* wp = (const short8*)wupb;
  #pragma unroll
  for (int kb=0; kb<2; ++kb) {
    short8 bfr[4];
    #pragma unroll
    for (int nt=0; nt<4; ++nt) bfr[nt] = wp[((parity*2+kb)*4+nt)*64 + lane];
    #pragma unroll
    for (int mt=0; mt<4; ++mt) {
      short8 a = stage[(kb*16 + w*4 + mt)*64 + lane];
      #pragma unroll
      for (int nt=0; nt<4; ++nt)
        acc[mt][nt] = __builtin_amdgcn_mfma_f32_16x16x32_bf16(a, bfr[nt], acc[mt][nt], 0,0,0);
    }
  }

  __syncthreads();
  short* trb = (short*)smem;
  #pragma unroll
  for (int mt=0; mt<4; ++mt)
    #pragma unroll
    for (int nt=0; nt<4; ++nt)
      #pragma unroll
      for (int r=0; r<4; ++r)
        trb[(w*64 + mt*16 + (lane>>4)*4 + r)*68 + nt*16 + (lane&15)] = f2bf(acc[mt][nt][r]);
  __syncthreads();

  int ip = chunk*256 + tid;
  int X = 2*(ip>>6) + (parity>>1), Y = 2*(ip&63) + (parity&1);
  short* dst = Ub + (((long)(b*8+t)*16384 + X*128 + Y)*64);
  const short* src = trb + tid*68;
  #pragma unroll
  for (int k=0; k<16; ++k)
    *(short4v*)(dst + k*4) = *(const short4v*)(src + k*4);
}

// ---------------- attention (bilinear-resized A) fused with 128->32 MLP -> HM (bf16 channel-last)
__global__ __launch_bounds__(256) void k_ctxmlp(const float* __restrict__ x2,
        const float* __restrict__ attn, const float* __restrict__ Wmlp,
        const float* __restrict__ bmlp, short* __restrict__ HMb) {
  int t = blockIdx.y, b = blockIdx.z;
  int pos = blockIdx.x*256 + threadIdx.x;    // x*128+y
  __shared__ float la[8192];                 // [n][ix][iy][s], 4*16*16*8
  float4* la4 = (float4*)la;
  const float4* g4 = (const float4*)attn;
  #pragma unroll
  for (int k=0;k<8;++k) {
    int i = k*256 + (int)threadIdx.x;        // float4 index: (n,ix,iy,s4)
    int s4 = i & 1, iy = (i>>1)&15, ix = (i>>5)&15, n = i>>9;
    la4[i] = g4[((((n*2+b)*16+ix)*16+iy)*8+t)*2 + s4];
  }
  __syncthreads();
  int x = pos >> 7, y = pos & 127;
  float ux = (x+0.5f)*0.125f - 0.5f;
  float uy = (y+0.5f)*0.125f - 0.5f;
  int ix0 = (int)floorf(ux), iy0 = (int)floorf(uy);
  float fx = ux - (float)ix0, fy = uy - (float)iy0;
  int ixa = max(ix0,0), ixb = min(ix0+1,15);
  int iya = max(iy0,0), iyb = min(iy0+1,15);
  float w00=(1.f-fx)*(1.f-fy), w01=(1.f-fx)*fy, w10=fx*(1.f-fy), w11=fx*fy;
  float a[4][8];
  #pragma unroll
  for (int n=0;n<4;++n) {
    const float4* p00 = la4 + ((n*16+ixa)*16+iya)*2;
    const float4* p01 = la4 + ((n*16+ixa)*16+iyb)*2;
    const float4* p10 = la4 + ((n*16+ixb)*16+iya)*2;
    const float4* p11 = la4 + ((n*16+ixb)*16+iyb)*2;
    #pragma unroll
    for (int q=0;q<2;++q) {
      float4 c00=p00[q], c01=p01[q], c10=p10[q], c11=p11[q];
      a[n][q*4+0] = w00*c00.x + w01*c01.x + w10*c10.x + w11*c11.x;
      a[n][q*4+1] = w00*c00.y + w01*c01.y + w10*c10.y + w11*c11.y;
      a[n][q*4+2] = w00*c00.z + w01*c01.z + w10*c10.z + w11*c11.z;
      a[n][q*4+3] = w00*c00.w + w01*c01.w + w10*c10.w + w11*c11.w;
    }
  }
  float acc[32];
  #pragma unroll
  for (int o=0;o<32;++o) acc[o] = bmlp[o];
  const float* x2p = x2 + b*4194304 + pos;
  #pragma unroll 4
  for (int c=0;c<32;++c) {
    float xr[8];
    #pragma unroll
    for (int s=0;s<8;++s) xr[s] = x2p[(c*8+s)*16384];
    #pragma unroll
    for (int n=0;n<4;++n) {
      float ctx = 0.f;
      #pragma unroll
      for (int s=0;s<8;++s) ctx = fmaf(a[n][s], xr[s], ctx);
      const float* wrow = Wmlp + (c*4+n)*32;
      #pragma unroll
      for (int o=0;o<32;++o) acc[o] = fmaf(ctx, wrow[o], acc[o]);
    }
  }
  short8* hp = (short8*)(HMb + ((long)((b*8+t)*16384 + pos)) * 32);
  #pragma unroll
  for (int g=0; g<4; ++g) {
    short8 v;
    #pragma unroll
    for (int j=0;j<8;++j) v[j] = f2bf(acc[g*8+j]);
    hp[g] = v;
  }
}

// ---------------- stats over channel-last bf16 [262144 pos][32 ch]
__global__ __launch_bounds__(256) void k_stats_cl(const unsigned* __restrict__ src, float* __restrict__ st) {
  __shared__ float sb[64];
  if (threadIdx.x < 64) sb[threadIdx.x] = 0.f;
  __syncthreads();
  int cp = threadIdx.x & 15;          // channel pair index
  int pg = threadIdx.x >> 4;          // 0..15
  long pbase = (long)blockIdx.x * 256;
  float s0=0.f,q0=0.f,s1=0.f,q1=0.f;
  #pragma unroll 4
  for (int it = 0; it < 16; ++it) {
    long pos = pbase + it*16 + pg;
    unsigned d = src[pos*16 + cp];
    float v0 = bf2f((short)(d & 0xffffu));
    float v1 = bf2f((short)(d >> 16));
    s0+=v0; q0+=v0*v0; s1+=v1; q1+=v1*v1;
  }
  s0 += __shfl_xor(s0,16); s0 += __shfl_xor(s0,32);
  q0 += __shfl_xor(q0,16); q0 += __shfl_xor(q0,32);
  s1 += __shfl_xor(s1,16); s1 += __shfl_xor(s1,32);
  q1 += __shfl_xor(q1,16); q1 += __shfl_xor(q1,32);
  if ((threadIdx.x & 63) < 16) {
    atomicAdd(&sb[2*cp],    s0); atomicAdd(&sb[2*cp+1],    s1);
    atomicAdd(&sb[32+2*cp], q0); atomicAdd(&sb[32+2*cp+1], q1);
  }
  __syncthreads();
  if (threadIdx.x < 64) atomicAdd(&st[threadIdx.x], sb[threadIdx.x]);
}

__global__ void k_finalize(const float* __restrict__ st, const float* __restrict__ g,
                           const float* __restrict__ be, float* __restrict__ sc, float* __restrict__ sh) {
  int c = threadIdx.x;
  if (c < 32) {
    float mean = st[c] * (1.f/262144.f);
    float var  = st[32+c] * (1.f/262144.f) - mean*mean;
    float s = g[c] / sqrtf(var + EPSV);
    sc[c] = s;
    sh[c] = be[c] - mean*s;
  }
}

// ---------------- 3x3 conv via bf16 MFMA implicit GEMM, CL bf16 in/out, fused output stats.
// chunk0 = bn_relu(srcCL) (32ch); chunks 1..NCHUNK-1 = raw bf16 CL from srcU (64ch).
template<int NCHUNK>
__global__ __launch_bounds__(256) void k_conv_mfma(
    const short* __restrict__ srcCL, const short* __restrict__ srcU,
    const short* __restrict__ wb, const float* __restrict__ bias,
    const float* __restrict__ sc, const float* __restrict__ sh,
    short* __restrict__ dstCL, float* __restrict__ st) {
  __shared__ __align__(16) char smem[25920];   // stage 324*40*2B | tr 256*32*2B
  __shared__ float sbuf[64];
  short* stage = (short*)smem;

  int t = blockIdx.y, b = blockIdx.z;
  int x0 = (int)(blockIdx.x >> 3) * 16, y0 = (int)(blockIdx.x & 7) * 16;
  int tid = threadIdx.x, lane = tid & 63, w = tid >> 6;
  if (tid < 64) sbuf[tid] = 0.f;

  float bias0 = bias[lane & 15], bias1 = bias[16 + (lane & 15)];
  floatx4 acc[4][2];
  #pragma unroll
  for (int mt=0; mt<4; ++mt) {
    acc[mt][0] = (floatx4){bias0,bias0,bias0,bias0};
    acc[mt][1] = (floatx4){bias1,bias1,bias1,bias1};
  }
  long slab = (long)(b*8+t)*16384;

  for (int cc=0; cc<NCHUNK; ++cc) {
    __syncthreads();
    if (cc == 0) {
      #pragma unroll
      for (int g=0; g<4; ++g) {
        float s0=sc[g*8+0],s1=sc[g*8+1],s2=sc[g*8+2],s3=sc[g*8+3];
        float s4=sc[g*8+4],s5=sc[g*8+5],s6=sc[g*8+6],s7=sc[g*8+7];
        float h0=sh[g*8+0],h1=sh[g*8+1],h2=sh[g*8+2],h3=sh[g*8+3];
        float h4=sh[g*8+4],h5=sh[g*8+5],h6=sh[g*8+6],h7=sh[g*8+7];
        for (int p=tid; p<324; p+=256) {
          int r = p/18, c = p - r*18;
          int X = x0 - 1 + r, Y = y0 - 1 + c;
          short8 val = (short8)0;
          if ((unsigned)X < 128u && (unsigned)Y < 128u) {
            short8 raw = *(const short8*)(srcCL + ((slab + X*128 + Y) * 32 + g*8));
            val[0]=f2bf(fmaxf(fmaf(bf2f(raw[0]),s0,h0),0.f));
            val[1]=f2bf(fmaxf(fmaf(bf2f(raw[1]),s1,h1),0.f));
            val[2]=f2bf(fmaxf(fmaf(bf2f(raw[2]),s2,h2),0.f));
            val[3]=f2bf(fmaxf(fmaf(bf2f(raw[3]),s3,h3),0.f));
            val[4]=f2bf(fmaxf(fmaf(bf2f(raw[4]),s4,h4),0.f));
            val[5]=f2bf(fmaxf(fmaf(bf2f(raw[5]),s5,h5),0.f));
            val[6]=f2bf(fmaxf(fmaf(bf2f(raw[6]),s6,h6),0.f));
            val[7]=f2bf(fmaxf(fmaf(bf2f(raw[7]),s7,h7),0.f));
          }
          *(short8*)(stage + p*40 + g*8) = val;
        }
      }
    } else {
      int cbase = (cc-1)*32;
      #pragma unroll
      for (int g=0; g<4; ++g) {
        for (int p=tid; p<324; p+=256) {
          int r = p/18, c = p - r*18;
          int X = x0 - 1 + r, Y = y0 - 1 + c;
          short8 val = (short8)0;
          if ((unsigned)X < 128u && (unsigned)Y < 128u) {
            val = *(const short8*)(srcU + ((slab + X*128 + Y) * 64 + cbase + g*8));
          }
          *(short8*)(stage + p*40 + g*8) = val;
        }
      }
    }
    __syncthreads();
    const short8* wbp = (const short8*)wb + (long)cc*9*2*64;
    #pragma unroll
    for (int tap=0; tap<9; ++tap) {
      int dy = tap/3, dx = tap - dy*3;
      short8 b0 = wbp[(tap*2+0)*64 + lane];
      short8 b1 = wbp[(tap*2+1)*64 + lane];
      #pragma unroll
      for (int mt=0; mt<4; ++mt) {
        int p = (w*4 + mt + dy)*18 + (lane & 15) + dx;
        short8 a = *(const short8*)(stage + p*40 + (lane>>4)*8);
        acc[mt][0] = __builtin_amdgcn_mfma_f32_16x16x32_bf16(a, b0, acc[mt][0], 0,0,0);
        acc[mt][1] = __builtin_amdgcn_mfma_f32_16x16x32_bf16(a, b1, acc[mt][1], 0,0,0);
      }
    }
  }

  // per-channel partial stats from acc (channels col and col+16)
  float s0=0.f,q0=0.f,s1=0.f,q1=0.f;
  #pragma unroll
  for (int mt=0; mt<4; ++mt)
    #pragma unroll
    for (int r=0; r<4; ++r) {
      float v0 = acc[mt][0][r]; s0 += v0; q0 += v0*v0;
      float v1 = acc[mt][1][r]; s1 += v1; q1 += v1*v1;
    }
  s0 += __shfl_xor(s0,16); s0 += __shfl_xor(s0,32);
  q0 += __shfl_xor(q0,16); q0 += __shfl_xor(q0,32);
  s1 += __shfl_xor(s1,16); s1 += __shfl_xor(s1,32);
  q1 += __shfl_xor(q1,16); q1 += __shfl_xor(q1,32);

  __syncthreads();
  if (lane < 16) {
    atomicAdd(&sbuf[lane],    s0); atomicAdd(&sbuf[16+lane], s1);
    atomicAdd(&sbuf[32+lane], q0); atomicAdd(&sbuf[48+lane], q1);
  }
  // transpose to [pos][ch] bf16
  short* tr = (short*)smem;
  #pragma unroll
  for (int mt=0; mt<4; ++mt) {
    int prow = w*4 + mt;
    #pragma unroll
    for (int nt=0; nt<2; ++nt) {
      #pragma unroll
      for (int r=0; r<4; ++r) {
        int m = (lane>>4)*4 + r;
        tr[(prow*16 + m)*32 + nt*16 + (lane&15)] = f2bf(acc[mt][nt][r]);
      }
    }
  }
  __syncthreads();
  int px = tid >> 4, py = tid & 15;
  short8* d8 = (short8*)(dstCL + ((slab + (long)(x0+px)*128 + (y0+py))*32));
  const short8* s8 = (const short8*)(tr + tid*32);
  d8[0]=s8[0]; d8[1]=s8[1]; d8[2]=s8[2]; d8[3]=s8[3];
  if (tid < 64) atomicAdd(&st[tid], sbuf[tid]);
}

// ---------------- final BN+ReLU: C2b (bf16 CL) -> out (fp32 planar)
__global__ __launch_bounds__(256) void k_bnrelu2(const short* __restrict__ C2b,
        const float* __restrict__ sc, const float* __restrict__ sh,
        float* __restrict__ out) {
  __shared__ float tb[10592];   // [ch][pos] at addr ch*321 + pos + (pos>>5)*8
  int t = blockIdx.y, b = blockIdx.z;
  int posbase = blockIdx.x * 256;
  int tid = threadIdx.x;
  long slab = (long)(b*8+t)*16384;
  {
    const short8* sp = (const short8*)(C2b + (slab + posbase + tid)*32);
    int pi = tid + (tid>>5)*8;
    #pragma unroll
    for (int g=0; g<4; ++g) {
      short8 v = sp[g];
      #pragma unroll
      for (int j=0; j<8; ++j) {
        int ch = g*8+j;
        tb[ch*321 + pi] = fmaxf(fmaf(bf2f(v[j]), sc[ch], sh[ch]), 0.f);
      }
    }
  }
  __syncthreads();
  int ch = tid >> 3, pg = tid & 7;
  float* op = out + ((long)(b*32+ch)*8 + t)*16384 + posbase + pg*32;
  const float* tp = tb + ch*321 + pg*40;
  #pragma unroll
  for (int k=0; k<8; ++k) {
    float4 v;
    v.x = tp[k*4+0]; v.y = tp[k*4+1]; v.z = tp[k*4+2]; v.w = tp[k*4+3];
    *(float4*)(op + k*4) = v;
  }
}

extern "C" void kernel_launch(void* const* d_in, const int* in_sizes, int n_in,
                              void* d_out, int out_size, void* d_ws, size_t ws_size,
                              hipStream_t stream) {
  (void)in_sizes; (void)n_in; (void)out_size; (void)ws_size;
  const float* x1   = (const float*)d_in[0];
  const float* x2   = (const float*)d_in[1];
  const float* attn = (const float*)d_in[2];
  const float* Wup  = (const float*)d_in[3];
  const float* bup  = (const float*)d_in[4];
  const float* Wmlp = (const float*)d_in[5];
  const float* bmlp = (const float*)d_in[6];
  const float* gmlp = (const float*)d_in[7];
  const float* bemlp= (const float*)d_in[8];
  const float* Wc1  = (const float*)d_in[9];
  const float* bc1  = (const float*)d_in[10];
  const float* gc1  = (const float*)d_in[11];
  const float* bec1 = (const float*)d_in[12];
  const float* Wc2  = (const float*)d_in[13];
  const float* bc2  = (const float*)d_in[14];
  const float* gc2  = (const float*)d_in[15];
  const float* bec2 = (const float*)d_in[16];
  float* ws  = (float*)d_ws;
  float* out = (float*)d_out;

  short* Ub   = (short*)(ws + UB_OFF);
  short* HMb  = (short*)(ws + HMB_OFF);
  short* C1b  = (short*)(ws + C1B_OFF);
  short* C2b  = (short*)(ws + C2B_OFF);
  short* wb1  = (short*)(ws + WB1_OFF);
  short* wb2  = (short*)(ws + WB2_OFF);
  short* wupb = (short*)(ws + WUP_OFF);
  float* st1  = ws + ST_OFF;
  float* st2  = st1 + 64;
  float* st3  = st2 + 64;
  float* sc1  = ws + SC_OFF;  float* sh1 = sc1+32;
  float* sc2  = sh1+32;       float* sh2 = sc2+32;
  float* sc3  = sh2+32;       float* sh3 = sc3+32;

  hipMemsetAsync(st1, 0, 192*sizeof(float), stream);
  k_repackb<<<108, 256, 0, stream>>>(Wc1, Wc2, Wup, wb1, wb2, wupb);
  k_up_mfma<<<dim3(64,8,2), 256, 0, stream>>>(x1, wupb, bup, Ub);
  k_ctxmlp<<<dim3(64,8,2), 256, 0, stream>>>(x2, attn, Wmlp, bmlp, HMb);
  k_stats_cl<<<1024, 256, 0, stream>>>((const unsigned*)HMb, st1);
  k_finalize<<<1, 32, 0, stream>>>(st1, gmlp, bemlp, sc1, sh1);
  k_conv_mfma<3><<<dim3(64,8,2), 256, 0, stream>>>(HMb, Ub, wb1, bc1, sc1, sh1, C1b, st2);
  k_finalize<<<1, 32, 0, stream>>>(st2, gc1, bec1, sc2, sh2);
  k_conv_mfma<1><<<dim3(64,8,2), 256, 0, stream>>>(C1b, nullptr, wb2, bc2, sc2, sh2, C2b, st3);
  k_finalize<<<1, 32, 0, stream>>>(st3, gc2, bec2, sc3, sh3);
  k_bnrelu2<<<dim3(64,8,2), 256, 0, stream>>>(C2b, sc3, sh3, out);
}